// Round 1
// baseline (3196.772 us; speedup 1.0000x reference)
//
#include <hip/hip_runtime.h>

#define BATCH   8
#define NPTS    8192
#define NPOINT  1024
#define NSAMPLE 32
#define CHANC   32
#define OUTC    35          // 3 xyz + 32 point channels
#define R2      0.0625f     // 0.25^2

// ---------------------------------------------------------------------------
// Kernel 1: furthest point sampling. One block per batch, 1024 threads,
// 8 points per thread held in registers. Bit-exact fp32 (no contraction) so
// argmax decisions match the numpy reference exactly.
// ---------------------------------------------------------------------------
__global__ __launch_bounds__(1024) void fps_kernel(const float* __restrict__ xyz,
                                                   float* __restrict__ new_xyz) {
#pragma clang fp contract(off)
    const int b = blockIdx.x;
    const int t = threadIdx.x;
    const float* bx = xyz + (size_t)b * NPTS * 3;

    // thread t owns points j = t + 1024*i, i in [0,8)
    float px[8], py[8], pz[8], dist[8];
#pragma unroll
    for (int i = 0; i < 8; ++i) {
        const int j = t + (i << 10);
        px[i] = bx[j * 3 + 0];
        py[i] = bx[j * 3 + 1];
        pz[i] = bx[j * 3 + 2];
        dist[i] = 1e38f;
    }

    __shared__ float rv[16], rxs[16], rys[16], rzs[16];
    __shared__ int   ri[16];
    __shared__ float bc[3];

    // seed: xyz[b, 0]
    float lx = bx[0], ly = bx[1], lz = bx[2];
    if (t == 0) {
        float* o = new_xyz + (size_t)b * NPOINT * 3;
        o[0] = lx; o[1] = ly; o[2] = lz;
    }

    for (int s = 1; s < NPOINT; ++s) {
        // --- local update + argmax over this thread's 8 points ---
        float bestv = -1.0f;
        int   bi    = 0;
#pragma unroll
        for (int i = 0; i < 8; ++i) {
            const float dx = px[i] - lx;
            const float dy = py[i] - ly;
            const float dz = pz[i] - lz;
            const float d2 = (dx * dx + dy * dy) + dz * dz;   // contract off -> exact
            const float d  = fminf(dist[i], d2);
            dist[i] = d;
            if (d > bestv) { bestv = d; bi = i; }             // strict > keeps lowest j
        }
        // coords of local winner (static select chain, no dynamic indexing)
        float bxv = px[0], byv = py[0], bzv = pz[0];
#pragma unroll
        for (int i = 1; i < 8; ++i) {
            if (bi == i) { bxv = px[i]; byv = py[i]; bzv = pz[i]; }
        }
        int besti = t + (bi << 10);   // global index; thread partition is index-strided

        // --- wave64 butterfly reduce (val, idx, coords), tie -> lower idx ---
#pragma unroll
        for (int off = 32; off > 0; off >>= 1) {
            const float ov = __shfl_xor(bestv, off);
            const int   oi = __shfl_xor(besti, off);
            const float ox = __shfl_xor(bxv, off);
            const float oy = __shfl_xor(byv, off);
            const float oz = __shfl_xor(bzv, off);
            if (ov > bestv || (ov == bestv && oi < besti)) {
                bestv = ov; besti = oi; bxv = ox; byv = oy; bzv = oz;
            }
        }

        // --- cross-wave reduce via LDS, serial scan by thread 0 ---
        const int w = t >> 6;
        if ((t & 63) == 0) {
            rv[w] = bestv; ri[w] = besti;
            rxs[w] = bxv; rys[w] = byv; rzs[w] = bzv;
        }
        __syncthreads();
        if (t == 0) {
            float v = rv[0]; int idx = ri[0];
            float X = rxs[0], Y = rys[0], Z = rzs[0];
#pragma unroll
            for (int q = 1; q < 16; ++q) {
                const float qv = rv[q]; const int qi = ri[q];
                if (qv > v || (qv == v && qi < idx)) {
                    v = qv; idx = qi; X = rxs[q]; Y = rys[q]; Z = rzs[q];
                }
            }
            bc[0] = X; bc[1] = Y; bc[2] = Z;
            float* o = new_xyz + ((size_t)b * NPOINT + s) * 3;
            o[0] = X; o[1] = Y; o[2] = Z;
        }
        __syncthreads();
        lx = bc[0]; ly = bc[1]; lz = bc[2];
    }
}

// ---------------------------------------------------------------------------
// Kernel 2: ball query + grouping. One wave per center (8192 waves).
// Ballot-based ordered collection of the first NSAMPLE in-radius indices
// (ascending), padded with the first hit; then coalesced 32x35 output store.
// ---------------------------------------------------------------------------
__global__ __launch_bounds__(256) void ballgroup_kernel(const float* __restrict__ xyz,
                                                        const float* __restrict__ points,
                                                        const float* __restrict__ new_xyz,
                                                        float* __restrict__ out) {
#pragma clang fp contract(off)
    const int lane = threadIdx.x & 63;
    const int w    = threadIdx.x >> 6;
    const int gw   = blockIdx.x * 4 + w;      // center id, 0..8191
    const int b    = gw >> 10;

    const float* bx  = xyz + (size_t)b * NPTS * 3;
    const float* cen = new_xyz + (size_t)gw * 3;
    const float cx = cen[0], cy = cen[1], cz = cen[2];

    __shared__ int idxbuf[4][NSAMPLE];

    int k = 0;
    for (int base = 0; base < NPTS; base += 64) {
        const int j = base + lane;
        const float dx = bx[j * 3 + 0] - cx;
        const float dy = bx[j * 3 + 1] - cy;
        const float dz = bx[j * 3 + 2] - cz;
        const float d2 = (dx * dx + dy * dy) + dz * dz;   // contract off -> exact
        const bool in = d2 < R2;
        const unsigned long long mask = __ballot(in);
        const int pre = __popcll(mask & ((1ull << lane) - 1ull));
        if (in && (k + pre) < NSAMPLE) idxbuf[w][k + pre] = j;
        k += __popcll(mask);
        if (k >= NSAMPLE) { k = NSAMPLE; break; }
    }
    // center is itself one of the points (d2 == 0), so k >= 1 always.
    const int first = idxbuf[w][0];

    float*       o    = out + (size_t)gw * NSAMPLE * OUTC;
    const float* prow = points + (size_t)b * NPTS * CHANC;
    for (int e = lane; e < NSAMPLE * OUTC; e += 64) {
        const int s = e / OUTC;
        const int c = e - s * OUTC;
        const int j = (s < k) ? idxbuf[w][s] : first;
        float v;
        if (c < 3) {
            const float cc = (c == 0) ? cx : (c == 1) ? cy : cz;
            v = bx[j * 3 + c] - cc;
        } else {
            v = prow[j * CHANC + (c - 3)];
        }
        o[e] = v;   // consecutive lanes -> consecutive addresses (coalesced)
    }
}

// ---------------------------------------------------------------------------
extern "C" void kernel_launch(void* const* d_in, const int* in_sizes, int n_in,
                              void* d_out, int out_size, void* d_ws, size_t ws_size,
                              hipStream_t stream) {
    const float* xyz    = (const float*)d_in[0];   // (8, 8192, 3)  fp32
    const float* points = (const float*)d_in[1];   // (8, 8192, 32) fp32
    float* new_xyz    = (float*)d_out;                         // (8,1024,3)
    float* new_points = new_xyz + (size_t)BATCH * NPOINT * 3;  // (8,1024,32,35)

    fps_kernel<<<BATCH, 1024, 0, stream>>>(xyz, new_xyz);
    ballgroup_kernel<<<(BATCH * NPOINT) / 4, 256, 0, stream>>>(xyz, points, new_xyz, new_points);
}

// Round 2
// 1432.170 us; speedup vs baseline: 2.2321x; 2.2321x over previous
//
#include <hip/hip_runtime.h>

#define BATCH   8
#define NPTS    8192
#define NPOINT  1024
#define NSAMPLE 32
#define CHANC   32
#define OUTC    35          // 3 xyz + 32 point channels
#define R2      0.0625f     // 0.25^2

// ---------------------------------------------------------------------------
// Kernel 1: furthest point sampling. One block per batch, 1024 threads,
// 8 points per thread in registers. Bit-exact fp32 (no contraction).
// Argmax via packed u64 (float_bits<<32 | ~idx): unsigned max == argmax with
// tie -> lowest index (valid because all candidate values are >= 0).
// xyz staged in LDS as float4 so winner coords = one broadcast ds_read_b128.
// ---------------------------------------------------------------------------
__global__ __launch_bounds__(1024) void fps_kernel(const float* __restrict__ xyz,
                                                   float* __restrict__ new_xyz) {
#pragma clang fp contract(off)
    const int b = blockIdx.x;
    const int t = threadIdx.x;
    const float* bx = xyz + (size_t)b * NPTS * 3;

    __shared__ float4 pts[NPTS];                       // 128 KB
    __shared__ unsigned long long partial[16];
    __shared__ unsigned long long winner;

    // thread t owns points j = t + 1024*i, i in [0,8)
    float px[8], py[8], pz[8], dist[8];
#pragma unroll
    for (int i = 0; i < 8; ++i) {
        const int j = t + (i << 10);
        const float x = bx[j * 3 + 0];
        const float y = bx[j * 3 + 1];
        const float z = bx[j * 3 + 2];
        px[i] = x; py[i] = y; pz[i] = z;
        dist[i] = 1e38f;
        pts[j] = make_float4(x, y, z, 0.0f);
    }
    __syncthreads();

    // seed: xyz[b, 0]
    float4 c0 = pts[0];
    float lx = c0.x, ly = c0.y, lz = c0.z;
    if (t == 0) {
        float* o = new_xyz + (size_t)b * NPOINT * 3;
        o[0] = lx; o[1] = ly; o[2] = lz;
    }

    for (int s = 1; s < NPOINT; ++s) {
        // --- local update + argmax over this thread's 8 points ---
        float bestv = -1.0f;
        int   bi    = 0;
#pragma unroll
        for (int i = 0; i < 8; ++i) {
            const float dx = px[i] - lx;
            const float dy = py[i] - ly;
            const float dz = pz[i] - lz;
            const float d2 = (dx * dx + dy * dy) + dz * dz;   // contract off -> exact
            const float d  = fminf(dist[i], d2);
            dist[i] = d;
            if (d > bestv) { bestv = d; bi = i; }             // strict > keeps lowest j
        }
        const int besti = t + (bi << 10);
        // pack: value bits (nonneg float -> integer-ordered) | ~idx (tie -> low idx)
        unsigned long long packed =
            ((unsigned long long)__float_as_uint(bestv) << 32) | (unsigned)(~besti);

        // --- wave64 butterfly max ---
#pragma unroll
        for (int off = 32; off > 0; off >>= 1) {
            const unsigned long long o = __shfl_xor(packed, off);
            if (o > packed) packed = o;
        }
        if ((t & 63) == 0) partial[t >> 6] = packed;
        __syncthreads();

        // --- wave 0 reduces the 16 partials in 4 shuffle steps ---
        if (t < 64) {
            unsigned long long v = (t < 16) ? partial[t] : 0ull;  // 0 < any real candidate
#pragma unroll
            for (int off = 8; off > 0; off >>= 1) {
                const unsigned long long o = __shfl_xor(v, off);
                if (o > v) v = o;
            }
            if (t == 0) winner = v;
        }
        __syncthreads();

        const unsigned long long wv = winner;
        const int idx = (int)(~(unsigned)(wv & 0xffffffffull));
        const float4 c = pts[idx];                      // broadcast read
        lx = c.x; ly = c.y; lz = c.z;
        if (t == 0) {
            float* o = new_xyz + ((size_t)b * NPOINT + s) * 3;
            o[0] = lx; o[1] = ly; o[2] = lz;
        }
    }
}

// ---------------------------------------------------------------------------
// Kernel 2: ball query + grouping. One wave per center (8192 waves).
// Ballot-based ordered collection of the first NSAMPLE in-radius indices
// (ascending), padded with the first hit; then coalesced 32x35 output store.
// ---------------------------------------------------------------------------
__global__ __launch_bounds__(256) void ballgroup_kernel(const float* __restrict__ xyz,
                                                        const float* __restrict__ points,
                                                        const float* __restrict__ new_xyz,
                                                        float* __restrict__ out) {
#pragma clang fp contract(off)
    const int lane = threadIdx.x & 63;
    const int w    = threadIdx.x >> 6;
    const int gw   = blockIdx.x * 4 + w;      // center id, 0..8191
    const int b    = gw >> 10;

    const float* bx  = xyz + (size_t)b * NPTS * 3;
    const float* cen = new_xyz + (size_t)gw * 3;
    const float cx = cen[0], cy = cen[1], cz = cen[2];

    __shared__ int idxbuf[4][NSAMPLE];

    int k = 0;
    for (int base = 0; base < NPTS; base += 64) {
        const int j = base + lane;
        const float dx = bx[j * 3 + 0] - cx;
        const float dy = bx[j * 3 + 1] - cy;
        const float dz = bx[j * 3 + 2] - cz;
        const float d2 = (dx * dx + dy * dy) + dz * dz;   // contract off -> exact
        const bool in = d2 < R2;
        const unsigned long long mask = __ballot(in);
        const int pre = __popcll(mask & ((1ull << lane) - 1ull));
        if (in && (k + pre) < NSAMPLE) idxbuf[w][k + pre] = j;
        k += __popcll(mask);
        if (k >= NSAMPLE) { k = NSAMPLE; break; }
    }
    // center is itself one of the points (d2 == 0), so k >= 1 always.
    const int first = idxbuf[w][0];

    float*       o    = out + (size_t)gw * NSAMPLE * OUTC;
    const float* prow = points + (size_t)b * NPTS * CHANC;
    for (int e = lane; e < NSAMPLE * OUTC; e += 64) {
        const int s = e / OUTC;
        const int c = e - s * OUTC;
        const int j = (s < k) ? idxbuf[w][s] : first;
        float v;
        if (c < 3) {
            const float cc = (c == 0) ? cx : (c == 1) ? cy : cz;
            v = bx[j * 3 + c] - cc;
        } else {
            v = prow[j * CHANC + (c - 3)];
        }
        o[e] = v;   // consecutive lanes -> consecutive addresses (coalesced)
    }
}

// ---------------------------------------------------------------------------
extern "C" void kernel_launch(void* const* d_in, const int* in_sizes, int n_in,
                              void* d_out, int out_size, void* d_ws, size_t ws_size,
                              hipStream_t stream) {
    const float* xyz    = (const float*)d_in[0];   // (8, 8192, 3)  fp32
    const float* points = (const float*)d_in[1];   // (8, 8192, 32) fp32
    float* new_xyz    = (float*)d_out;                         // (8,1024,3)
    float* new_points = new_xyz + (size_t)BATCH * NPOINT * 3;  // (8,1024,32,35)

    fps_kernel<<<BATCH, 1024, 0, stream>>>(xyz, new_xyz);
    ballgroup_kernel<<<(BATCH * NPOINT) / 4, 256, 0, stream>>>(xyz, points, new_xyz, new_points);
}

// Round 3
// 1277.494 us; speedup vs baseline: 2.5024x; 1.1211x over previous
//
#include <hip/hip_runtime.h>

#define BATCH   8
#define NPTS    8192
#define NPOINT  1024
#define NSAMPLE 32
#define CHANC   32
#define OUTC    35          // 3 xyz + 32 point channels
#define R2      0.0625f     // 0.25^2

// ---------------------------------------------------------------------------
// Kernel 1: furthest point sampling. One block per batch, 512 threads,
// 16 CONTIGUOUS points per thread (j = t*16+i) so that lane order == index
// order: argmax tie-break to lowest global index reduces to "lowest set lane"
// after a value-only max reduction. Bit-exact fp32 (no contraction).
// One __syncthreads per iteration; per-wave partials double-buffered by
// iteration parity; every wave redundantly reduces the 8 partials.
// ---------------------------------------------------------------------------
__global__ __launch_bounds__(512) void fps_kernel(const float* __restrict__ xyz,
                                                  float* __restrict__ new_xyz) {
#pragma clang fp contract(off)
    const int b    = blockIdx.x;
    const int t    = threadIdx.x;
    const int lane = t & 63;
    const int w    = t >> 6;              // wave id, 0..7
    const float* bx = xyz + (size_t)b * NPTS * 3;

    __shared__ float4 pts[NPTS];          // 128 KB
    __shared__ float  pv[2][8];
    __shared__ int    pi[2][8];

    // thread t owns points j = t*16 + i, i in [0,16): 48 consecutive floats
    float px[16], py[16], pz[16], dist[16];
    {
        float f[48];
        float4* fq = (float4*)f;
        const float4* s4 = (const float4*)bx + t * 12;
#pragma unroll
        for (int q = 0; q < 12; ++q) fq[q] = s4[q];
#pragma unroll
        for (int i = 0; i < 16; ++i) {
            px[i] = f[3 * i + 0];
            py[i] = f[3 * i + 1];
            pz[i] = f[3 * i + 2];
            dist[i] = 1e38f;
            pts[t * 16 + i] = make_float4(px[i], py[i], pz[i], 0.0f);
        }
    }
    __syncthreads();

    // seed: xyz[b, 0]
    float4 c0 = pts[0];
    float lx = c0.x, ly = c0.y, lz = c0.z;
    if (t == 0) {
        float* o = new_xyz + (size_t)b * NPOINT * 3;
        o[0] = lx; o[1] = ly; o[2] = lz;
    }

    for (int s = 1; s < NPOINT; ++s) {
        // --- local update + argmax over this thread's 16 points ---
        float bestv = -1.0f;
        int   bi    = 0;
#pragma unroll
        for (int i = 0; i < 16; ++i) {
            const float dx = px[i] - lx;
            const float dy = py[i] - ly;
            const float dz = pz[i] - lz;
            const float d2 = (dx * dx + dy * dy) + dz * dz;   // contract off -> exact
            const float d  = fminf(dist[i], d2);
            dist[i] = d;
            if (d > bestv) { bestv = d; bi = i; }             // strict > keeps lowest i
        }
        const int besti = (t << 4) + bi;

        // --- wave64 value-only butterfly max (all lanes get wave max) ---
        float v = bestv;
#pragma unroll
        for (int off = 32; off > 0; off >>= 1)
            v = fmaxf(v, __shfl_xor(v, off));
        // lowest lane achieving the max == lowest global index in this wave
        const unsigned long long m = __ballot(bestv == v);
        const int src  = (int)__builtin_ctzll(m);
        const int widx = __shfl(besti, src);

        const int par = s & 1;
        if (lane == 0) { pv[par][w] = v; pi[par][w] = widx; }
        __syncthreads();

        // --- every wave redundantly reduces the 8 partials ---
        const float fv = pv[par][lane & 7];                   // broadcast-class read
        float mv = fv;
#pragma unroll
        for (int off = 4; off > 0; off >>= 1)
            mv = fmaxf(mv, __shfl_xor(mv, off));
        const unsigned long long fm = __ballot(fv == mv);
        const int fsrc = (int)__builtin_ctzll(fm);            // in [0,8): lowest wave
        const int idx  = __shfl(pi[par][lane & 7], fsrc);

        const float4 c = pts[idx];                            // broadcast read
        lx = c.x; ly = c.y; lz = c.z;
        if (t == 0) {
            float* o = new_xyz + ((size_t)b * NPOINT + s) * 3;
            o[0] = lx; o[1] = ly; o[2] = lz;
        }
    }
}

// ---------------------------------------------------------------------------
// Kernel 2: ball query + grouping. One wave per center (8192 waves).
// Ballot-based ordered collection of the first NSAMPLE in-radius indices
// (ascending), padded with the first hit; then coalesced 32x35 output store.
// ---------------------------------------------------------------------------
__global__ __launch_bounds__(256) void ballgroup_kernel(const float* __restrict__ xyz,
                                                        const float* __restrict__ points,
                                                        const float* __restrict__ new_xyz,
                                                        float* __restrict__ out) {
#pragma clang fp contract(off)
    const int lane = threadIdx.x & 63;
    const int w    = threadIdx.x >> 6;
    const int gw   = blockIdx.x * 4 + w;      // center id, 0..8191
    const int b    = gw >> 10;

    const float* bx  = xyz + (size_t)b * NPTS * 3;
    const float* cen = new_xyz + (size_t)gw * 3;
    const float cx = cen[0], cy = cen[1], cz = cen[2];

    __shared__ int idxbuf[4][NSAMPLE];

    int k = 0;
    for (int base = 0; base < NPTS; base += 64) {
        const int j = base + lane;
        const float dx = bx[j * 3 + 0] - cx;
        const float dy = bx[j * 3 + 1] - cy;
        const float dz = bx[j * 3 + 2] - cz;
        const float d2 = (dx * dx + dy * dy) + dz * dz;   // contract off -> exact
        const bool in = d2 < R2;
        const unsigned long long mask = __ballot(in);
        const int pre = __popcll(mask & ((1ull << lane) - 1ull));
        if (in && (k + pre) < NSAMPLE) idxbuf[w][k + pre] = j;
        k += __popcll(mask);
        if (k >= NSAMPLE) { k = NSAMPLE; break; }
    }
    // center is itself one of the points (d2 == 0), so k >= 1 always.
    const int first = idxbuf[w][0];

    float*       o    = out + (size_t)gw * NSAMPLE * OUTC;
    const float* prow = points + (size_t)b * NPTS * CHANC;
    for (int e = lane; e < NSAMPLE * OUTC; e += 64) {
        const int s = e / OUTC;
        const int c = e - s * OUTC;
        const int j = (s < k) ? idxbuf[w][s] : first;
        float v;
        if (c < 3) {
            const float cc = (c == 0) ? cx : (c == 1) ? cy : cz;
            v = bx[j * 3 + c] - cc;
        } else {
            v = prow[j * CHANC + (c - 3)];
        }
        o[e] = v;   // consecutive lanes -> consecutive addresses (coalesced)
    }
}

// ---------------------------------------------------------------------------
extern "C" void kernel_launch(void* const* d_in, const int* in_sizes, int n_in,
                              void* d_out, int out_size, void* d_ws, size_t ws_size,
                              hipStream_t stream) {
    const float* xyz    = (const float*)d_in[0];   // (8, 8192, 3)  fp32
    const float* points = (const float*)d_in[1];   // (8, 8192, 32) fp32
    float* new_xyz    = (float*)d_out;                         // (8,1024,3)
    float* new_points = new_xyz + (size_t)BATCH * NPOINT * 3;  // (8,1024,32,35)

    fps_kernel<<<BATCH, 512, 0, stream>>>(xyz, new_xyz);
    ballgroup_kernel<<<(BATCH * NPOINT) / 4, 256, 0, stream>>>(xyz, points, new_xyz, new_points);
}

// Round 5
// 1021.651 us; speedup vs baseline: 3.1290x; 1.2504x over previous
//
#include <hip/hip_runtime.h>

#define BATCH   8
#define NPTS    8192
#define NPOINT  1024
#define NSAMPLE 32
#define CHANC   32
#define OUTC    35          // 3 xyz + 32 point channels
#define R2      0.0625f     // 0.25^2

typedef float v2f __attribute__((ext_vector_type(2)));

// DPP helpers --------------------------------------------------------------
// ctrl as template param: __builtin_amdgcn_update_dpp requires ICE operands.
template <int CTRL>
__device__ __forceinline__ float dpp_max_step(float v) {
    // old = v, bound_ctrl=false -> invalid lanes contribute v (identity for max)
    int r = __builtin_amdgcn_update_dpp(__float_as_int(v), __float_as_int(v),
                                        CTRL, 0xf, 0xf, false);
    return fmaxf(v, __int_as_float(r));
}
#define DPP_ROW_SHR(n)  (0x110 | (n))
#define DPP_BCAST15     0x142
#define DPP_BCAST31     0x143

// ---------------------------------------------------------------------------
// Kernel 1: furthest point sampling. One block per batch, 512 threads,
// 16 contiguous points per thread (j = t*16+i). Bit-exact fp32 (no
// contraction); packed-f32 (v_pk_*) distance update. Wave argmax via DPP
// row_shr/row_bcast max + readlane(63) + ballot; leader lane writes a packed
// u64 (value<<32 | ~idx) partial. One barrier/iter (parity double-buffer);
// all waves redundantly scan the 8 partials. Winner coords from XOR-swizzled
// float4 LDS mirror (uniform -> broadcast read, swizzle kills staging-write
// bank conflicts).
// ---------------------------------------------------------------------------
__global__ __launch_bounds__(512) void fps_kernel(const float* __restrict__ xyz,
                                                  float* __restrict__ new_xyz) {
#pragma clang fp contract(off)
    const int b    = blockIdx.x;
    const int t    = threadIdx.x;
    const int lane = t & 63;
    const int w    = t >> 6;              // wave id, 0..7
    const float* bx = xyz + (size_t)b * NPTS * 3;

    __shared__ float4 pts[NPTS];                    // 128 KB, XOR-swizzled
    __shared__ unsigned long long partial[2][8];

    // thread t owns points j = t*16 + i, i in [0,16): 48 consecutive floats
    v2f px[8], py[8], pz[8], dist[8];
    {
        float f[48];
        float4* fq = (float4*)f;
        const float4* s4 = (const float4*)bx + t * 12;
#pragma unroll
        for (int q = 0; q < 12; ++q) fq[q] = s4[q];
#pragma unroll
        for (int p = 0; p < 8; ++p) {
            px[p] = (v2f){f[6 * p + 0], f[6 * p + 3]};
            py[p] = (v2f){f[6 * p + 1], f[6 * p + 4]};
            pz[p] = (v2f){f[6 * p + 2], f[6 * p + 5]};
            dist[p] = (v2f){1e38f, 1e38f};
        }
#pragma unroll
        for (int i = 0; i < 16; ++i) {
            const int j  = t * 16 + i;
            const int js = j ^ ((j >> 4) & 7);      // bank swizzle
            pts[js] = make_float4(f[3 * i + 0], f[3 * i + 1], f[3 * i + 2], 0.0f);
        }
    }
    __syncthreads();

    // seed: xyz[b, 0]  (swizzle(0) == 0)
    float4 c0 = pts[0];
    float lx = c0.x, ly = c0.y, lz = c0.z;
    if (t == 0) {
        float* o = new_xyz + (size_t)b * NPOINT * 3;
        o[0] = lx; o[1] = ly; o[2] = lz;
    }

    for (int s = 1; s < NPOINT; ++s) {
        // --- packed update + argmax over this thread's 16 points ---
        const v2f lx2 = (v2f){lx, lx};
        const v2f ly2 = (v2f){ly, ly};
        const v2f lz2 = (v2f){lz, lz};
        float bestv = -1.0f;
        int   bi    = 0;
#pragma unroll
        for (int p = 0; p < 8; ++p) {
            const v2f dx = px[p] - lx2;
            const v2f dy = py[p] - ly2;
            const v2f dz = pz[p] - lz2;
            const v2f d2 = (dx * dx + dy * dy) + dz * dz;   // contract off -> exact
            const float d0 = fminf(dist[p].x, d2.x);
            const float d1 = fminf(dist[p].y, d2.y);
            dist[p] = (v2f){d0, d1};
            if (d0 > bestv) { bestv = d0; bi = 2 * p; }     // strict > keeps lowest i
            if (d1 > bestv) { bestv = d1; bi = 2 * p + 1; }
        }
        const int besti = (t << 4) + bi;

        // --- wave64 max via DPP (6 VALU steps, no LDS) ---
        float v = bestv;
        v = dpp_max_step<DPP_ROW_SHR(1)>(v);
        v = dpp_max_step<DPP_ROW_SHR(2)>(v);
        v = dpp_max_step<DPP_ROW_SHR(4)>(v);
        v = dpp_max_step<DPP_ROW_SHR(8)>(v);
        v = dpp_max_step<DPP_BCAST15>(v);
        v = dpp_max_step<DPP_BCAST31>(v);
        const float smax = __int_as_float(__builtin_amdgcn_readlane(__float_as_int(v), 63));

        // leader lane (lowest lane holding the max == lowest index) writes partial
        const unsigned long long m = __ballot(bestv == smax);
        const int par = s & 1;
        if (lane == (int)__builtin_ctzll(m)) {
            partial[par][w] = ((unsigned long long)__float_as_uint(smax) << 32)
                              | (unsigned)(~besti);
        }
        __syncthreads();

        // --- all lanes uniformly scan the 8 partials (broadcast reads) ---
        unsigned long long bp = partial[par][0];
#pragma unroll
        for (int q = 1; q < 8; ++q) {
            const unsigned long long o = partial[par][q];
            if (o > bp) bp = o;
        }
        const int idx = (int)(~(unsigned)bp);
        const int js  = idx ^ ((idx >> 4) & 7);
        const float4 c = pts[js];                           // uniform -> broadcast
        lx = c.x; ly = c.y; lz = c.z;
        if (t == 0) {
            float* o = new_xyz + ((size_t)b * NPOINT + s) * 3;
            o[0] = lx; o[1] = ly; o[2] = lz;
        }
    }
}

// ---------------------------------------------------------------------------
// Kernel 2: ball query + grouping. One wave per center (8192 waves).
// Ballot-based ordered collection of the first NSAMPLE in-radius indices
// (ascending), padded with the first hit; then coalesced 32x35 output store.
// ---------------------------------------------------------------------------
__global__ __launch_bounds__(256) void ballgroup_kernel(const float* __restrict__ xyz,
                                                        const float* __restrict__ points,
                                                        const float* __restrict__ new_xyz,
                                                        float* __restrict__ out) {
#pragma clang fp contract(off)
    const int lane = threadIdx.x & 63;
    const int w    = threadIdx.x >> 6;
    const int gw   = blockIdx.x * 4 + w;      // center id, 0..8191
    const int b    = gw >> 10;

    const float* bx  = xyz + (size_t)b * NPTS * 3;
    const float* cen = new_xyz + (size_t)gw * 3;
    const float cx = cen[0], cy = cen[1], cz = cen[2];

    __shared__ int idxbuf[4][NSAMPLE];

    int k = 0;
    for (int base = 0; base < NPTS; base += 64) {
        const int j = base + lane;
        const float dx = bx[j * 3 + 0] - cx;
        const float dy = bx[j * 3 + 1] - cy;
        const float dz = bx[j * 3 + 2] - cz;
        const float d2 = (dx * dx + dy * dy) + dz * dz;   // contract off -> exact
        const bool in = d2 < R2;
        const unsigned long long mask = __ballot(in);
        const int pre = __popcll(mask & ((1ull << lane) - 1ull));
        if (in && (k + pre) < NSAMPLE) idxbuf[w][k + pre] = j;
        k += __popcll(mask);
        if (k >= NSAMPLE) { k = NSAMPLE; break; }
    }
    // center is itself one of the points (d2 == 0), so k >= 1 always.
    const int first = idxbuf[w][0];

    float*       o    = out + (size_t)gw * NSAMPLE * OUTC;
    const float* prow = points + (size_t)b * NPTS * CHANC;
    for (int e = lane; e < NSAMPLE * OUTC; e += 64) {
        const int s = e / OUTC;
        const int c = e - s * OUTC;
        const int j = (s < k) ? idxbuf[w][s] : first;
        float v;
        if (c < 3) {
            const float cc = (c == 0) ? cx : (c == 1) ? cy : cz;
            v = bx[j * 3 + c] - cc;
        } else {
            v = prow[j * CHANC + (c - 3)];
        }
        o[e] = v;   // consecutive lanes -> consecutive addresses (coalesced)
    }
}

// ---------------------------------------------------------------------------
extern "C" void kernel_launch(void* const* d_in, const int* in_sizes, int n_in,
                              void* d_out, int out_size, void* d_ws, size_t ws_size,
                              hipStream_t stream) {
    const float* xyz    = (const float*)d_in[0];   // (8, 8192, 3)  fp32
    const float* points = (const float*)d_in[1];   // (8, 8192, 32) fp32
    float* new_xyz    = (float*)d_out;                         // (8,1024,3)
    float* new_points = new_xyz + (size_t)BATCH * NPOINT * 3;  // (8,1024,32,35)

    fps_kernel<<<BATCH, 512, 0, stream>>>(xyz, new_xyz);
    ballgroup_kernel<<<(BATCH * NPOINT) / 4, 256, 0, stream>>>(xyz, points, new_xyz, new_points);
}